// Round 3
// baseline (210.310 us; speedup 1.0000x reference)
//
#include <hip/hip_runtime.h>
#include <cstdint>
#include <cstddef>

typedef _Float16 f16;
typedef _Float16 f16x4 __attribute__((ext_vector_type(4)));
typedef _Float16 f16x8 __attribute__((ext_vector_type(8)));
typedef float    f32x4 __attribute__((ext_vector_type(4)));

#define CIN    128
#define COUT   256
#define HH     56
#define WW     56
#define HW     3136           // 56*56
#define PPDIM  3364           // 58*58 padded pixel plane
#define XPLANE (PPDIM*CIN)    // 430592 halves per batch image

__device__ __forceinline__ void gload16(const void* g, void* l) {
  __builtin_amdgcn_global_load_lds((const __attribute__((address_space(1))) unsigned int*)g,
                                   (__attribute__((address_space(3))) unsigned int*)l,
                                   16, 0, 0);
}

// ---------------------------------------------------------------------------
// Prepass 1 (v3, LDS-free): x (NCHW f32) -> zero-padded NHWC f16.
// One block per (b, padded-row pr). lane = w. Each lane gathers 8 channels
// with per-instruction-coalesced scalar loads (fixed c => 56 consecutive
// dwords per wave) and writes one contiguous f16x8. Pad rows/cols written
// here too (workspace is re-poisoned every call -> must cover everything).
// ---------------------------------------------------------------------------
__global__ __launch_bounds__(256) void xpad_kernel(const float* __restrict__ x,
                                                   f16* __restrict__ xp) {
  const int bid = blockIdx.x;             // 32*58 = 1856
  const int pr  = bid % 58;
  const int b   = bid / 58;
  const int tid = threadIdx.x;
  f16* orow = xp + (size_t)b * XPLANE + (size_t)pr * 58 * CIN;

  if (pr == 0 || pr == 57) {              // full pad row: 58*128 halves
    for (int i = tid; i < 928; i += 256)
      *(f16x8*)(orow + (size_t)i * 8) = (f16x8){};
    return;
  }
  const int h = pr - 1;
  const int wave = tid >> 6, lane = tid & 63;
  if (tid < 32) {                         // pad columns px=0 and px=57
    int px = (tid < 16) ? 0 : 57;
    int cg = tid & 15;
    *(f16x8*)(orow + (size_t)px * CIN + cg * 8) = (f16x8){};
  }
  if (lane < 56) {
    const float* xb = x + (size_t)b * CIN * HW + (size_t)h * WW + lane;
    f16* op = orow + (size_t)(lane + 1) * CIN;
    #pragma unroll
    for (int cg = 0; cg < 4; ++cg) {
      const int c0 = (wave * 4 + cg) * 8;
      f16x8 v;
      #pragma unroll
      for (int j = 0; j < 8; ++j)
        v[j] = (f16)xb[(size_t)(c0 + j) * HW];
      *(f16x8*)(op + c0) = v;
    }
  }
}

// ---------------------------------------------------------------------------
// Prepass 2: w (OIHW f32) -> sign -> f16, stored as the EXACT (pre-swizzled)
// LDS image the main kernel stages with linear global_load_lds.
// 3-bit st-swizzle baked in: physical half = logical ^ ((co&7)<<3).
// K order: k = kidx*128 + c ; step s (BK=64) covers k in [s*64, s*64+64).
// ---------------------------------------------------------------------------
__global__ __launch_bounds__(256) void wprep_kernel(const float* __restrict__ w,
                                                    f16* __restrict__ wt) {
  int t = blockIdx.x * 256 + threadIdx.x;   // 294912 exact
  int s     = t >> 14;                      // K-step (16384 halves each)
  int hidx  = t & 16383;
  int co    = hidx >> 6;
  int khalf = (hidx & 63) ^ ((co & 7) << 3);  // un-swizzle to logical k
  int kidx  = s >> 1;
  int c     = ((s & 1) << 6) + khalf;
  float v = w[(size_t)co * 1152 + c * 9 + kidx];
  wt[t] = (f16)((v > 0.f) ? 1.f : (v < 0.f ? -1.f : 0.f));
}

// ---------------------------------------------------------------------------
// Main implicit-GEMM: tile 128 px x 256 co, K=1152, BK=64 (18 steps).
// 8 waves (2 px x 4 co), each 64x64 via mfma_f32_16x16x32_f16.
// Staging: global_load_lds dwordx4; LDS images carry the FULL 3-bit XOR
// swizzle (byte ^= (row&7)<<4) via pre-swizzled per-lane SOURCE addresses,
// giving conflict-free ds_read_b128 (8 distinct 16B slots per 8 rows).
// ---------------------------------------------------------------------------
__global__ __launch_bounds__(512) void bconv_main(
    const f16* __restrict__ xp, const f16* __restrict__ wt,
    const float* __restrict__ bias, float* __restrict__ out) {
  __shared__ __align__(16) f16 Alds[128 * 64];   // 16 KB  [px][64 halves]
  __shared__ __align__(16) f16 Blds[256 * 64];   // 32 KB  [co][64 halves]
  const int tid = threadIdx.x;
  const int p0  = blockIdx.x * 128;              // 784 tiles exact

  // ---- staging maps (hoisted) ----
  const int wave = tid >> 6, lane = tid & 63;
  const int pxl  = tid >> 3;                     // LDS row this lane fills
  const int kx_s = ((tid & 7) << 4) ^ ((pxl & 7) << 4);  // swizzled src k-byte
  const int pga  = p0 + pxl;
  const int pgb  = pga + 64;
  const int ba = pga / HW, ra = pga % HW;
  const int bb = pgb / HW, rb = pgb % HW;
  const int ha = ra / WW, wa = ra % WW;
  const int hb = rb / WW, wb = rb % WW;
  const char* xpB = (const char*)xp;
  const char* srcA0 = xpB + 2 * ((size_t)ba * XPLANE + (size_t)((ha + 1) * 58 + wa + 1) * CIN) + kx_s;
  const char* srcA1 = xpB + 2 * ((size_t)bb * XPLANE + (size_t)((hb + 1) * 58 + wb + 1) * CIN) + kx_s;
  char* AldsB = (char*)Alds;
  char* BldsB = (char*)Blds;
  char* dstA0 = AldsB + (wave << 10);
  char* dstA1 = AldsB + 8192 + (wave << 10);
  const char* wtB = (const char*)wt + (tid << 4);
  char* dstB = BldsB + (wave << 10);

  // ---- fragment maps ----
  const int wpx = wave >> 2;       // 0..1
  const int wco = wave & 3;        // 0..3
  const int l15 = lane & 15, l4 = lane >> 4;
  const int kxr = (l15 & 7) << 4;  // read-side swizzle (row low bits -> slot)
  const int rA = ((wpx << 6) + l15) << 7;   // byte row base in Alds
  const int rB = ((wco << 6) + l15) << 7;   // byte row base in Blds

  f32x4 acc[4][4];
  #pragma unroll
  for (int i = 0; i < 4; ++i)
    #pragma unroll
    for (int j = 0; j < 4; ++j) acc[i][j] = (f32x4){0.f, 0.f, 0.f, 0.f};

  #pragma unroll 1
  for (int s = 0; s < 18; ++s) {
    const int kidx = s >> 1, ch = s & 1;
    const int dh = kidx / 3 - 1, dw = kidx - (kidx / 3) * 3 - 1;
    const long toff = (long)(dh * 58 + dw) * 256 + ch * 128;
    gload16(srcA0 + toff, dstA0);
    gload16(srcA1 + toff, dstA1);
    const char* ws = wtB + (size_t)s * 32768;
    gload16(ws,         dstB);
    gload16(ws + 8192,  dstB + 8192);
    gload16(ws + 16384, dstB + 16384);
    gload16(ws + 24576, dstB + 24576);
    __syncthreads();

    #pragma unroll
    for (int kk = 0; kk < 2; ++kk) {
      const int ko = ((kk << 6) + (l4 << 4)) ^ kxr;
      f16x8 xf[4], wf[4];
      #pragma unroll
      for (int j = 0; j < 4; ++j)
        xf[j] = *(const f16x8*)(AldsB + rA + (j << 11) + ko);
      #pragma unroll
      for (int i = 0; i < 4; ++i)
        wf[i] = *(const f16x8*)(BldsB + rB + (i << 11) + ko);
      #pragma unroll
      for (int i = 0; i < 4; ++i)
        #pragma unroll
        for (int j = 0; j < 4; ++j)
          acc[i][j] = __builtin_amdgcn_mfma_f32_16x16x32_f16(wf[i], xf[j], acc[i][j], 0, 0, 0);
    }
    __syncthreads();
  }

  // Epilogue: D col (lane&15) = pixel; coalesced 64B runs along px.
  #pragma unroll
  for (int j = 0; j < 4; ++j) {
    const int pg = p0 + wpx * 64 + j * 16 + l15;
    const int bo = pg / HW;
    const int pr = pg % HW;
    float* ob = out + (size_t)bo * (COUT * HW) + pr;
    #pragma unroll
    for (int i = 0; i < 4; ++i) {
      const int cb2 = wco * 64 + i * 16 + l4 * 4;
      #pragma unroll
      for (int r = 0; r < 4; ++r) {
        const int co = cb2 + r;
        ob[(size_t)co * HW] = acc[i][j][r] + bias[co];
      }
    }
  }
}

extern "C" void kernel_launch(void* const* d_in, const int* in_sizes, int n_in,
                              void* d_out, int out_size, void* d_ws, size_t ws_size,
                              hipStream_t stream) {
  const float* x    = (const float*)d_in[0];
  const float* w    = (const float*)d_in[1];
  const float* bias = (const float*)d_in[2];
  float* out = (float*)d_out;

  f16* xp = (f16*)d_ws;                       // 32*430592 halves = 27.56 MB
  f16* wt = xp + (size_t)32 * XPLANE;         // 294912 halves    = 0.59 MB

  xpad_kernel<<<1856, 256, 0, stream>>>(x, xp);     // writes ALL of xp incl pads
  wprep_kernel<<<1152, 256, 0, stream>>>(w, wt);    // writes ALL of wt
  bconv_main<<<784, 512, 0, stream>>>(xp, wt, bias, out);
}